// Round 4
// baseline (23080.229 us; speedup 1.0000x reference)
//
#include <hip/hip_runtime.h>

#define NPTS   32768
#define DIM    256
#define KCODES 8192

#define BM 128
#define BN 512
#define BK 16
#define NSPLIT 2
#define HSP (BM + 4)   // padded LDS pitch: 132f = 528B, 16B-aligned, %32banks=4
#define CSP (BN + 4)   // 516f = 2064B, 16B-aligned, %32banks=4

// ---------------- kernel 0: row squared-norms ----------------
__global__ __launch_bounds__(256) void norms_kernel(const float* __restrict__ src,
                                                    float* __restrict__ dst) {
  int row = blockIdx.x * 4 + (threadIdx.x >> 6);
  int lane = threadIdx.x & 63;
  float4 a = reinterpret_cast<const float4*>(src)[row * (DIM / 4) + lane];
  float sx = a.x * a.x, sy = a.y * a.y, sz = a.z * a.z, sw = a.w * a.w;
  double s = (double)sx + (double)sy + (double)sz + (double)sw;
#pragma unroll
  for (int m = 32; m; m >>= 1) s += __shfl_xor(s, m, 64);
  if (lane == 0) dst[row] = (float)s;
}

// ---------------- kernel 1: fused distance GEMM + argmin (code-split) --------
// grid 512 = 256 point-blocks x 2 code-slices, XCD-chunked so each XCD's L2
// holds one 4MB codebook slice. Score arithmetic identical to the passing
// round-3 kernel: s = fl32( fl32(h2+c2) - 2*dot ), ascending-k fma chain,
// strict-< first-index argmin.
__global__ __launch_bounds__(512, 4) void argmin_kernel(
    const float* __restrict__ h, const float* __restrict__ cb,
    const float* __restrict__ h2f, const float* __restrict__ c2f,
    float* __restrict__ bestval, int* __restrict__ bestidx) {
  __shared__ float hs[BK][HSP];   // 8.25 KB
  __shared__ float cs[BK][CSP];   // 32.25 KB
  const int t = threadIdx.x;
  const int ct = t & 31;
  const int pt = t >> 5;
  // XCD-chunked bijective swizzle: XCD(b)=b&7 gets contiguous virtual range
  const int b = blockIdx.x;
  const int v = (b & 7) * 64 + (b >> 3);
  const int sblk = v >> 8;              // 0..1  (code slice)
  const int pblk = v & 255;             // 0..255 (point block)
  const int p0 = pblk * BM;
  const int cbase = sblk * (KCODES / NSPLIT);

  float best[8];
  int besti[8];
  float h2r[8];
#pragma unroll
  for (int i = 0; i < 8; ++i) {
    best[i] = 3.4e38f;
    besti[i] = 0;
    h2r[i] = h2f[p0 + pt * 4 + ((i >> 2) << 6) + (i & 3)];
  }

#pragma unroll 1
  for (int cc = 0; cc < KCODES / NSPLIT / BN; ++cc) {
    const int c0 = cbase + cc * BN;
    float dot[8][16];
#pragma unroll
    for (int i = 0; i < 8; ++i)
#pragma unroll
      for (int j = 0; j < 16; ++j) dot[i][j] = 0.f;

#pragma unroll 1
    for (int dd = 0; dd < DIM / BK; ++dd) {
      const int d0 = dd * BK;
      // stage h tile (transposed scatter): 512 float4, one per thread
      {
        int p = t >> 2, k4 = (t & 3) << 2;
        float4 w = *reinterpret_cast<const float4*>(h + (p0 + p) * DIM + d0 + k4);
        hs[k4 + 0][p] = w.x; hs[k4 + 1][p] = w.y;
        hs[k4 + 2][p] = w.z; hs[k4 + 3][p] = w.w;
      }
      // stage c tile: 2048 float4, four per thread
#pragma unroll
      for (int l = 0; l < 4; ++l) {
        int F = t + l * 512;
        int c = F >> 2, k4 = (F & 3) << 2;
        float4 w = *reinterpret_cast<const float4*>(cb + (c0 + c) * DIM + d0 + k4);
        cs[k4 + 0][c] = w.x; cs[k4 + 1][c] = w.y;
        cs[k4 + 2][c] = w.z; cs[k4 + 3][c] = w.w;
      }
      __syncthreads();
#pragma unroll
      for (int k = 0; k < BK; ++k) {
        float hv[8], cv[16];
        *reinterpret_cast<float4*>(&hv[0]) = *reinterpret_cast<const float4*>(&hs[k][pt * 4]);
        *reinterpret_cast<float4*>(&hv[4]) = *reinterpret_cast<const float4*>(&hs[k][pt * 4 + 64]);
        *reinterpret_cast<float4*>(&cv[0])  = *reinterpret_cast<const float4*>(&cs[k][ct * 4]);
        *reinterpret_cast<float4*>(&cv[4])  = *reinterpret_cast<const float4*>(&cs[k][ct * 4 + 128]);
        *reinterpret_cast<float4*>(&cv[8])  = *reinterpret_cast<const float4*>(&cs[k][ct * 4 + 256]);
        *reinterpret_cast<float4*>(&cv[12]) = *reinterpret_cast<const float4*>(&cs[k][ct * 4 + 384]);
#pragma unroll
        for (int i = 0; i < 8; ++i)
#pragma unroll
          for (int j = 0; j < 16; ++j)
            dot[i][j] = fmaf(hv[i], cv[j], dot[i][j]);
      }
      __syncthreads();
    }
    // numpy-fp32 scores + running argmin (ascending code order -> first-min)
#pragma unroll
    for (int j = 0; j < 16; ++j) {
      int cl = c0 + (ct << 2) + ((j >> 2) << 7) + (j & 3);
      float cc2 = c2f[cl];
#pragma unroll
      for (int i = 0; i < 8; ++i) {
        float A = h2r[i] + cc2;          // fl32(h2 + c2)
        float s = A - 2.0f * dot[i][j];  // fl32(A - 2*dot)
        if (s < best[i]) { best[i] = s; besti[i] = cl; }
      }
    }
  }
  // cross-lane reduce over the 32 ct-lanes (same pt), lowest-index tiebreak
#pragma unroll
  for (int i = 0; i < 8; ++i) {
    float b1 = best[i];
    int i1 = besti[i];
#pragma unroll
    for (int m = 16; m; m >>= 1) {
      float so = __shfl_xor(b1, m, 64);
      int io = __shfl_xor(i1, m, 64);
      if (so < b1 || (so == b1 && io < i1)) { b1 = so; i1 = io; }
    }
    if (ct == 0) {
      int p = p0 + pt * 4 + ((i >> 2) << 6) + (i & 3);
      bestval[sblk * NPTS + p] = b1;
      bestidx[sblk * NPTS + p] = i1;
    }
  }
}

// ---------------- kernel 1b: merge the two code-slices ----------------
__global__ __launch_bounds__(256) void merge_kernel(
    const float* __restrict__ bestval, const int* __restrict__ bestidx,
    int* __restrict__ idx, float* __restrict__ out_idx_f) {
  int p = blockIdx.x * 256 + threadIdx.x;
  float v0 = bestval[p], v1 = bestval[NPTS + p];
  int i0 = bestidx[p], i1 = bestidx[NPTS + p];
  // strict <: on fp32 ties slice0 (lower indices) wins == np.argmin semantics
  int w = (v1 < v0) ? i1 : i0;
  idx[p] = w;
  out_idx_f[p] = (float)w;
}

// ---------------- kernel 2: gather z, write z_q, masked sq-sum partials ------
__global__ __launch_bounds__(256) void gather_kernel(
    const float* __restrict__ h, const float* __restrict__ cb,
    const unsigned char* __restrict__ maskb, const int* __restrict__ idx,
    float* __restrict__ zq, float* __restrict__ partial) {
  int p = blockIdx.x * 4 + (threadIdx.x >> 6);
  int lane = threadIdx.x & 63;
  int ci = idx[p];
  float4 hv = reinterpret_cast<const float4*>(h)[p * (DIM / 4) + lane];
  float4 zv = reinterpret_cast<const float4*>(cb)[ci * (DIM / 4) + lane];
  float4 q;
  q.x = hv.x + (zv.x - hv.x);
  q.y = hv.y + (zv.y - hv.y);
  q.z = hv.z + (zv.z - hv.z);
  q.w = hv.w + (zv.w - hv.w);
  reinterpret_cast<float4*>(zq)[p * (DIM / 4) + lane] = q;
  float dx = hv.x - zv.x, dy = hv.y - zv.y, dz = hv.z - zv.z, dw = hv.w - zv.w;
  float s = (maskb[p] != 0) ? (dx * dx + dy * dy + dz * dz + dw * dw) : 0.f;
#pragma unroll
  for (int m = 32; m; m >>= 1) s += __shfl_xor(s, m, 64);
  __shared__ float bs[4];
  if (lane == 0) bs[threadIdx.x >> 6] = s;
  __syncthreads();
  if (threadIdx.x == 0) partial[blockIdx.x] = bs[0] + bs[1] + bs[2] + bs[3];
}

// ---------------- kernel 3: deterministic finalize ----------------
__global__ __launch_bounds__(256) void finalize_kernel(
    const float* __restrict__ partial, const unsigned char* __restrict__ maskb,
    float* __restrict__ out_losses) {
  __shared__ float red[256];
  __shared__ int redi[256];
  float s = 0.f;
  for (int i = threadIdx.x; i < NPTS / 4; i += 256) s += partial[i];
  int cnt = 0;
  for (int i = threadIdx.x; i < NPTS; i += 256) cnt += (maskb[i] != 0);
  red[threadIdx.x] = s;
  redi[threadIdx.x] = cnt;
  __syncthreads();
  for (int step = 128; step; step >>= 1) {
    if (threadIdx.x < step) {
      red[threadIdx.x] += red[threadIdx.x + step];
      redi[threadIdx.x] += redi[threadIdx.x + step];
    }
    __syncthreads();
  }
  if (threadIdx.x == 0) {
    float denom = (float)redi[0] * (float)DIM + 1e-8f;
    float loss = red[0] / denom;
    out_losses[0] = loss;   // commit_loss
    out_losses[1] = loss;   // codebook_loss (identical in forward)
  }
}

extern "C" void kernel_launch(void* const* d_in, const int* in_sizes, int n_in,
                              void* d_out, int out_size, void* d_ws, size_t ws_size,
                              hipStream_t stream) {
  const float* h = (const float*)d_in[0];
  const unsigned char* maskb = (const unsigned char*)d_in[1];
  const float* cb = (const float*)d_in[2];

  float* out = (float*)d_out;
  float* zq = out;                              // NPTS*DIM
  float* out_idx_f = out + NPTS * DIM;          // NPTS
  float* out_losses = out + NPTS * DIM + NPTS;  // 2

  char* ws = (char*)d_ws;
  float* h2f = (float*)(ws + 0);                 // 128KB [0,128K)
  float* c2f = (float*)(ws + (128 << 10));       // 32KB  [128K,160K)
  float* bestval = (float*)(ws + (160 << 10));   // 256KB [160K,416K)
  int* bestidx = (int*)(ws + (416 << 10));       // 256KB [416K,672K)
  int* idx = (int*)(ws + (672 << 10));           // 128KB [672K,800K)
  float* partial = (float*)(ws + (800 << 10));   // 32KB  [800K,832K)

  hipLaunchKernelGGL(norms_kernel, dim3(NPTS / 4), dim3(256), 0, stream, h, h2f);
  hipLaunchKernelGGL(norms_kernel, dim3(KCODES / 4), dim3(256), 0, stream, cb, c2f);
  hipLaunchKernelGGL(argmin_kernel, dim3(256 * NSPLIT), dim3(512), 0, stream,
                     h, cb, h2f, c2f, bestval, bestidx);
  hipLaunchKernelGGL(merge_kernel, dim3(NPTS / 256), dim3(256), 0, stream,
                     bestval, bestidx, idx, out_idx_f);
  hipLaunchKernelGGL(gather_kernel, dim3(NPTS / 4), dim3(256), 0, stream,
                     h, cb, maskb, idx, zq, partial);
  hipLaunchKernelGGL(finalize_kernel, dim3(1), dim3(256), 0, stream,
                     partial, maskb, out_losses);
}

// Round 5
// 3340.401 us; speedup vs baseline: 6.9094x; 6.9094x over previous
//
#include <hip/hip_runtime.h>

#define NPTS   32768
#define DIM    256
#define KCODES 8192

#define BM 128
#define BN 512
#define BK 16
#define NSPLIT 2
#define HSP (BM + 4)   // padded LDS pitch: 132f = 528B, 16B-aligned
#define CSP (BN + 4)   // 516f = 2064B, 16B-aligned

// ---------------- kernel 0: row squared-norms ----------------
__global__ __launch_bounds__(256) void norms_kernel(const float* __restrict__ src,
                                                    float* __restrict__ dst) {
  int row = blockIdx.x * 4 + (threadIdx.x >> 6);
  int lane = threadIdx.x & 63;
  float4 a = reinterpret_cast<const float4*>(src)[row * (DIM / 4) + lane];
  float sx = a.x * a.x, sy = a.y * a.y, sz = a.z * a.z, sw = a.w * a.w;
  double s = (double)sx + (double)sy + (double)sz + (double)sw;
#pragma unroll
  for (int m = 32; m; m >>= 1) s += __shfl_xor(s, m, 64);
  if (lane == 0) dst[row] = (float)s;
}

// ---------------- kernel 1: fused distance GEMM + argmin (code-split) --------
// grid 512 = 256 point-blocks x 2 code-slices, XCD-chunked. launch_bounds
// min-waves=2 so the allocator keeps ~128 VGPRs (r4's =4 forced 64 and
// spilled dot[8][16] to scratch: 121 GB HBM traffic, 7x slower).
__global__ __launch_bounds__(512, 2) void argmin_kernel(
    const float* __restrict__ h, const float* __restrict__ cb,
    const float* __restrict__ h2f, const float* __restrict__ c2f,
    float* __restrict__ bestval, int* __restrict__ bestidx) {
  __shared__ float hs[BK][HSP];   // 8.25 KB
  __shared__ float cs[BK][CSP];   // 32.25 KB
  const int t = threadIdx.x;
  const int ct = t & 31;
  const int pt = t >> 5;
  const int b = blockIdx.x;
  const int v = (b & 7) * 64 + (b >> 3);  // XCD-chunked bijective swizzle
  const int sblk = v >> 8;                // 0..1  (code slice)
  const int pblk = v & 255;               // 0..255 (point block)
  const int p0 = pblk * BM;
  const int cbase = sblk * (KCODES / NSPLIT);

  float best[8];
  int besti[8];
  float h2r[8];
#pragma unroll
  for (int i = 0; i < 8; ++i) {
    best[i] = 3.4e38f;
    besti[i] = 0;
    h2r[i] = h2f[p0 + pt * 4 + ((i >> 2) << 6) + (i & 3)];
  }

#pragma unroll 1
  for (int cc = 0; cc < KCODES / NSPLIT / BN; ++cc) {
    const int c0 = cbase + cc * BN;
    float dot[8][16];
#pragma unroll
    for (int i = 0; i < 8; ++i)
#pragma unroll
      for (int j = 0; j < 16; ++j) dot[i][j] = 0.f;

#pragma unroll 1
    for (int dd = 0; dd < DIM / BK; ++dd) {
      const int d0 = dd * BK;
      // stage h tile (transposed scatter): 512 float4, one per thread
      {
        int p = t >> 2, k4 = (t & 3) << 2;
        float4 w = *reinterpret_cast<const float4*>(h + (p0 + p) * DIM + d0 + k4);
        hs[k4 + 0][p] = w.x; hs[k4 + 1][p] = w.y;
        hs[k4 + 2][p] = w.z; hs[k4 + 3][p] = w.w;
      }
      // stage c tile: 2048 float4, four per thread
#pragma unroll
      for (int l = 0; l < 4; ++l) {
        int F = t + l * 512;
        int c = F >> 2, k4 = (F & 3) << 2;
        float4 w = *reinterpret_cast<const float4*>(cb + (c0 + c) * DIM + d0 + k4);
        cs[k4 + 0][c] = w.x; cs[k4 + 1][c] = w.y;
        cs[k4 + 2][c] = w.z; cs[k4 + 3][c] = w.w;
      }
      __syncthreads();
#pragma unroll
      for (int k = 0; k < BK; ++k) {
        float hv[8], cv[16];
        *reinterpret_cast<float4*>(&hv[0]) = *reinterpret_cast<const float4*>(&hs[k][pt * 4]);
        *reinterpret_cast<float4*>(&hv[4]) = *reinterpret_cast<const float4*>(&hs[k][pt * 4 + 64]);
        *reinterpret_cast<float4*>(&cv[0])  = *reinterpret_cast<const float4*>(&cs[k][ct * 4]);
        *reinterpret_cast<float4*>(&cv[4])  = *reinterpret_cast<const float4*>(&cs[k][ct * 4 + 128]);
        *reinterpret_cast<float4*>(&cv[8])  = *reinterpret_cast<const float4*>(&cs[k][ct * 4 + 256]);
        *reinterpret_cast<float4*>(&cv[12]) = *reinterpret_cast<const float4*>(&cs[k][ct * 4 + 384]);
#pragma unroll
        for (int i = 0; i < 8; ++i)
#pragma unroll
          for (int j = 0; j < 16; ++j)
            dot[i][j] = fmaf(hv[i], cv[j], dot[i][j]);
      }
      __syncthreads();
    }
    // numpy-fp32 scores + running argmin (ascending code order -> first-min)
#pragma unroll
    for (int j = 0; j < 16; ++j) {
      int cl = c0 + (ct << 2) + ((j >> 2) << 7) + (j & 3);
      float cc2 = c2f[cl];
#pragma unroll
      for (int i = 0; i < 8; ++i) {
        float A = h2r[i] + cc2;          // fl32(h2 + c2)
        float s = A - 2.0f * dot[i][j];  // fl32(A - 2*dot)
        if (s < best[i]) { best[i] = s; besti[i] = cl; }
      }
    }
  }
  // cross-lane reduce over the 32 ct-lanes (same pt), lowest-index tiebreak
#pragma unroll
  for (int i = 0; i < 8; ++i) {
    float b1 = best[i];
    int i1 = besti[i];
#pragma unroll
    for (int m = 16; m; m >>= 1) {
      float so = __shfl_xor(b1, m, 64);
      int io = __shfl_xor(i1, m, 64);
      if (so < b1 || (so == b1 && io < i1)) { b1 = so; i1 = io; }
    }
    if (ct == 0) {
      int p = p0 + pt * 4 + ((i >> 2) << 6) + (i & 3);
      bestval[sblk * NPTS + p] = b1;
      bestidx[sblk * NPTS + p] = i1;
    }
  }
}

// ---------------- kernel 1b: merge the two code-slices ----------------
__global__ __launch_bounds__(256) void merge_kernel(
    const float* __restrict__ bestval, const int* __restrict__ bestidx,
    int* __restrict__ idx, float* __restrict__ out_idx_f) {
  int p = blockIdx.x * 256 + threadIdx.x;
  float v0 = bestval[p], v1 = bestval[NPTS + p];
  int i0 = bestidx[p], i1 = bestidx[NPTS + p];
  // strict <: on fp32 ties slice0 (lower indices) wins == np.argmin semantics
  int w = (v1 < v0) ? i1 : i0;
  idx[p] = w;
  out_idx_f[p] = (float)w;
}

// ---------------- kernel 2: gather z, write z_q, masked sq-sum partials ------
__global__ __launch_bounds__(256) void gather_kernel(
    const float* __restrict__ h, const float* __restrict__ cb,
    const unsigned char* __restrict__ maskb, const int* __restrict__ idx,
    float* __restrict__ zq, float* __restrict__ partial) {
  int p = blockIdx.x * 4 + (threadIdx.x >> 6);
  int lane = threadIdx.x & 63;
  int ci = idx[p];
  float4 hv = reinterpret_cast<const float4*>(h)[p * (DIM / 4) + lane];
  float4 zv = reinterpret_cast<const float4*>(cb)[ci * (DIM / 4) + lane];
  float4 q;
  q.x = hv.x + (zv.x - hv.x);
  q.y = hv.y + (zv.y - hv.y);
  q.z = hv.z + (zv.z - hv.z);
  q.w = hv.w + (zv.w - hv.w);
  reinterpret_cast<float4*>(zq)[p * (DIM / 4) + lane] = q;
  float dx = hv.x - zv.x, dy = hv.y - zv.y, dz = hv.z - zv.z, dw = hv.w - zv.w;
  float s = (maskb[p] != 0) ? (dx * dx + dy * dy + dz * dz + dw * dw) : 0.f;
#pragma unroll
  for (int m = 32; m; m >>= 1) s += __shfl_xor(s, m, 64);
  __shared__ float bs[4];
  if (lane == 0) bs[threadIdx.x >> 6] = s;
  __syncthreads();
  if (threadIdx.x == 0) partial[blockIdx.x] = bs[0] + bs[1] + bs[2] + bs[3];
}

// ---------------- kernel 3: deterministic finalize ----------------
__global__ __launch_bounds__(256) void finalize_kernel(
    const float* __restrict__ partial, const unsigned char* __restrict__ maskb,
    float* __restrict__ out_losses) {
  __shared__ float red[256];
  __shared__ int redi[256];
  float s = 0.f;
  for (int i = threadIdx.x; i < NPTS / 4; i += 256) s += partial[i];
  int cnt = 0;
  for (int i = threadIdx.x; i < NPTS; i += 256) cnt += (maskb[i] != 0);
  red[threadIdx.x] = s;
  redi[threadIdx.x] = cnt;
  __syncthreads();
  for (int step = 128; step; step >>= 1) {
    if (threadIdx.x < step) {
      red[threadIdx.x] += red[threadIdx.x + step];
      redi[threadIdx.x] += redi[threadIdx.x + step];
    }
    __syncthreads();
  }
  if (threadIdx.x == 0) {
    float denom = (float)redi[0] * (float)DIM + 1e-8f;
    float loss = red[0] / denom;
    out_losses[0] = loss;   // commit_loss
    out_losses[1] = loss;   // codebook_loss (identical in forward)
  }
}

extern "C" void kernel_launch(void* const* d_in, const int* in_sizes, int n_in,
                              void* d_out, int out_size, void* d_ws, size_t ws_size,
                              hipStream_t stream) {
  const float* h = (const float*)d_in[0];
  const unsigned char* maskb = (const unsigned char*)d_in[1];
  const float* cb = (const float*)d_in[2];

  float* out = (float*)d_out;
  float* zq = out;                              // NPTS*DIM
  float* out_idx_f = out + NPTS * DIM;          // NPTS
  float* out_losses = out + NPTS * DIM + NPTS;  // 2

  char* ws = (char*)d_ws;
  float* h2f = (float*)(ws + 0);                 // 128KB [0,128K)
  float* c2f = (float*)(ws + (128 << 10));       // 32KB  [128K,160K)
  float* bestval = (float*)(ws + (160 << 10));   // 256KB [160K,416K)
  int* bestidx = (int*)(ws + (416 << 10));       // 256KB [416K,672K)
  int* idx = (int*)(ws + (672 << 10));           // 128KB [672K,800K)
  float* partial = (float*)(ws + (800 << 10));   // 32KB  [800K,832K)

  hipLaunchKernelGGL(norms_kernel, dim3(NPTS / 4), dim3(256), 0, stream, h, h2f);
  hipLaunchKernelGGL(norms_kernel, dim3(KCODES / 4), dim3(256), 0, stream, cb, c2f);
  hipLaunchKernelGGL(argmin_kernel, dim3(256 * NSPLIT), dim3(512), 0, stream,
                     h, cb, h2f, c2f, bestval, bestidx);
  hipLaunchKernelGGL(merge_kernel, dim3(NPTS / 256), dim3(256), 0, stream,
                     bestval, bestidx, idx, out_idx_f);
  hipLaunchKernelGGL(gather_kernel, dim3(NPTS / 4), dim3(256), 0, stream,
                     h, cb, maskb, idx, zq, partial);
  hipLaunchKernelGGL(finalize_kernel, dim3(1), dim3(256), 0, stream,
                     partial, maskb, out_losses);
}